// Round 3
// baseline (38.165 us; speedup 1.0000x reference)
//
#include <hip/hip_runtime.h>
#include <hip/hip_bf16.h>
#include <math.h>

#define D_MODEL 512
#define N_PEAKS 500
#define BATCH   1024
#define BLOCK   256

// out[b][2k]   = sum_n w[b,n] * sin(idx[b,n] * omega_k)
// out[b][2k+1] = sum_n w[b,n] * cos(idx[b,n] * omega_k)
// idx = ceil(loc*10), omega_k = exp(2k * -ln(10000)/512).
//
// All angle math is done in REVOLUTIONS so the native trans unit can be used
// directly: v_sin_f32/v_cos_f32 compute sin/cos(2*pi*x). One v_fract reduces
// rev (up to ~4775) into [0,1). This avoids ocml __sinf's multi-instruction
// radian-domain range reduction.
__global__ __launch_bounds__(BLOCK)
void SpectrumEncoding_84164179132426_kernel(const float* __restrict__ loc,
                                            const float* __restrict__ inten,
                                            float* __restrict__ out) {
    __shared__ float2 s_iw[N_PEAKS];   // {ceil(loc*10) as float, masked weight}

    const int b = blockIdx.x;
    const int t = threadIdx.x;

    for (int n = t; n < N_PEAKS; n += BLOCK) {
        float l    = loc[b * N_PEAKS + n];
        float idxf = ceilf(l * 10.0f);            // matches jnp.ceil(loc*10)
        float w    = inten[b * N_PEAKS + n];
        // Reference zeroes pe row 0 -> mask that peak's weight (cos(0)=1).
        s_iw[n] = make_float2(idxf, (idxf == 0.0f) ? 0.0f : w);
    }
    __syncthreads();

    // omega_k / (2*pi), computed once per thread in f64 for table-grade
    // precision, then rounded to f32.
    const double cd = -log(10000.0) / (double)D_MODEL;
    const float wk_rev = (float)(exp((double)(2 * t) * cd) / (2.0 * M_PI));

    float acc_s = 0.0f, acc_c = 0.0f;

#pragma unroll 8
    for (int n = 0; n < N_PEAKS; ++n) {
        const float2 iw  = s_iw[n];                         // broadcast ds_read_b64
        const float  rev = iw.x * wk_rev;                   // angle in revolutions
        const float  r   = __builtin_amdgcn_fractf(rev);    // v_fract_f32 -> [0,1)
        const float  s   = __builtin_amdgcn_sinf(r);        // v_sin_f32: sin(2*pi*r)
        const float  c   = __builtin_amdgcn_cosf(r);        // v_cos_f32: cos(2*pi*r)
        acc_s = fmaf(iw.y, s, acc_s);
        acc_c = fmaf(iw.y, c, acc_c);
    }

    *(float2*)(out + b * D_MODEL + 2 * t) = make_float2(acc_s, acc_c);
}

extern "C" void kernel_launch(void* const* d_in, const int* in_sizes, int n_in,
                              void* d_out, int out_size, void* d_ws, size_t ws_size,
                              hipStream_t stream) {
    const float* loc   = (const float*)d_in[0];   // [1024, 500] f32
    const float* inten = (const float*)d_in[1];   // [1024, 500] f32
    // d_in[2] (pe table) intentionally unused: recomputed analytically.
    float*       out   = (float*)d_out;           // [1024, 512] f32

    SpectrumEncoding_84164179132426_kernel<<<BATCH, BLOCK, 0, stream>>>(loc, inten, out);
}